// Round 2
// baseline (108.083 us; speedup 1.0000x reference)
//
#include <hip/hip_runtime.h>
#include <hip/hip_bf16.h>

#define NSTATES 8
#define HD      1024
#define NBATCH  16384

// output layout (flat fp32, return order)
#define OUT_MEAS 0
#define OUT_CP   16777216
#define OUT_ENT  16777224
#define OUT_COH  16777225
#define OUT_AD   16777226
#define OUT_PH   16785418

typedef __attribute__((ext_vector_type(8))) short short8;
typedef __attribute__((ext_vector_type(4))) float f32x4;

__device__ __forceinline__ short f2bf(float f) {
    union { float f; unsigned u; } x; x.f = f;
    unsigned r = x.u + 0x7fffu + ((x.u >> 16) & 1u);  // RNE
    return (short)(r >> 16);
}

// block-wide sum; valid result on thread 0 only. red = shared float[16].
__device__ __forceinline__ float blockReduceTo0(float v, float* red) {
    #pragma unroll
    for (int o = 32; o > 0; o >>= 1) v += __shfl_down(v, o, 64);
    int lane = threadIdx.x & 63, wid = threadIdx.x >> 6;
    __syncthreads();                 // protect red[] from previous use
    if (lane == 0) red[wid] = v;
    __syncthreads();
    float r = 0.f;
    if (wid == 0) {
        r = (lane < 16) ? red[lane] : 0.f;
        #pragma unroll
        for (int o = 8; o > 0; o >>= 1) r += __shfl_down(r, o, 64);
    }
    return r;
}

// ---------------- K1: amplitude pipeline (1 block, 1024 threads) ----------------
__global__ __launch_bounds__(1024) void k_amps(const float* __restrict__ AR,
                                               const float* __restrict__ AI,
                                               const float* __restrict__ H,
                                               float* __restrict__ out,
                                               float* __restrict__ w) {
    __shared__ float red[16];
    __shared__ float norms[NSTATES];
    __shared__ float Ur[NSTATES][NSTATES], Ui[NSTATES][NSTATES];

    const int d = threadIdx.x;  // hidden index
    float arv[NSTATES], aiv[NSTATES];
    #pragma unroll
    for (int s = 0; s < NSTATES; s++) {
        arv[s] = AR[s * HD + d];
        aiv[s] = AI[s * HD + d];
    }
    #pragma unroll
    for (int s = 0; s < NSTATES; s++) {
        float r = blockReduceTo0(arv[s] * arv[s] + aiv[s] * aiv[s], red);
        if (threadIdx.x == 0) norms[s] = r;
    }
    // U = expm(-i*dt*A), A = 0.5*(H+H^T). ||A||~1e-4 -> 3-term Taylor exact in fp32.
    if (threadIdx.x == 0) {
        float A[8][8], A2[8][8], A3[8][8];
        for (int i = 0; i < 8; i++)
            for (int j = 0; j < 8; j++)
                A[i][j] = 0.5f * (H[i * 8 + j] + H[j * 8 + i]) * 0.01f;  // DT/PLANCK
        for (int i = 0; i < 8; i++)
            for (int j = 0; j < 8; j++) {
                float acc = 0.f;
                for (int k = 0; k < 8; k++) acc += A[i][k] * A[k][j];
                A2[i][j] = acc;
            }
        for (int i = 0; i < 8; i++)
            for (int j = 0; j < 8; j++) {
                float acc = 0.f;
                for (int k = 0; k < 8; k++) acc += A2[i][k] * A[k][j];
                A3[i][j] = acc;
            }
        for (int i = 0; i < 8; i++)
            for (int j = 0; j < 8; j++) {
                Ur[i][j] = ((i == j) ? 1.f : 0.f) - 0.5f * A2[i][j];       // cos(A)
                Ui[i][j] = -(A[i][j] - A3[i][j] * (1.f / 6.f));            // -sin(A)
            }
    }
    __syncthreads();

    #pragma unroll
    for (int s = 0; s < NSTATES; s++) {
        float inv = 1.0f / sqrtf(norms[s] + 1e-8f);
        arv[s] *= inv;
        aiv[s] *= inv;
    }
    float nr[NSTATES], ni[NSTATES];
    #pragma unroll
    for (int s = 0; s < NSTATES; s++) {
        float xr = 0.f, xi = 0.f;
        #pragma unroll
        for (int t = 0; t < NSTATES; t++) {
            float ur = Ur[s][t], ui = Ui[s][t];
            xr += ur * arv[t] - ui * aiv[t];
            xi += ur * aiv[t] + ui * arv[t];
        }
        nr[s] = xr; ni[s] = xi;
    }
    float dist[NSTATES], csum = 0.f, sabs = 0.f;
    #pragma unroll
    for (int s = 0; s < NSTATES; s++) {
        dist[s] = nr[s] * nr[s] + ni[s] * ni[s];
        csum += dist[s];
        sabs += sqrtf(dist[s]);
    }
    #pragma unroll
    for (int s = 0; s < NSTATES; s++) {
        out[OUT_AD + s * HD + d] = dist[s];
        out[OUT_PH + s * HD + d] = atan2f(ni[s], nr[s]);
        w[s * HD + d] = nr[s];
    }
    float cinv = 1.0f / (csum + 1e-8f);
    #pragma unroll
    for (int s = 0; s < NSTATES; s++) {
        float r = blockReduceTo0(dist[s] * cinv, red);
        if (threadIdx.x == 0) out[OUT_CP + s] = r * (1.0f / HD);
    }
    float lam = blockReduceTo0(csum, red);
    float sa  = blockReduceTo0(sabs, red);
    if (threadIdx.x == 0) {
        out[OUT_ENT] = -(lam * logf(lam + 1e-12f));
        out[OUT_COH] = sa * sa - lam;
    }
}

// ---------------- K2: X (fp32) -> Xb (bf16), vectorized ----------------
__global__ __launch_bounds__(256) void k_castX(const float* __restrict__ X,
                                               short* __restrict__ Xb) {
    int idx = blockIdx.x * 256 + threadIdx.x;   // chunk of 8 elems
    const float* src = X + (size_t)idx * 8;
    float4 f0 = *reinterpret_cast<const float4*>(src);
    float4 f1 = *reinterpret_cast<const float4*>(src + 4);
    short8 v;
    v[0] = f2bf(f0.x); v[1] = f2bf(f0.y); v[2] = f2bf(f0.z); v[3] = f2bf(f0.w);
    v[4] = f2bf(f1.x); v[5] = f2bf(f1.y); v[6] = f2bf(f1.z); v[7] = f2bf(f1.w);
    *reinterpret_cast<short8*>(Xb + (size_t)idx * 8) = v;
}

// ------- K3: fused project + transpose: Mt[e,d] = bf16( sum_s w[s,e]*P[s,d,e] ) -
__global__ __launch_bounds__(256) void k_project_t(const float* __restrict__ P,
                                                   const float* __restrict__ w,
                                                   short* __restrict__ Mt) {
    __shared__ float tile[64][65];
    int d0 = (blockIdx.x >> 4) * 64;
    int e0 = (blockIdx.x & 15) * 64;
    int tx = threadIdx.x & 63, ty = threadIdx.x >> 6;
    float wv[NSTATES];
    #pragma unroll
    for (int s = 0; s < NSTATES; s++) wv[s] = w[s * HD + e0 + tx];
    #pragma unroll
    for (int j = 0; j < 16; j++) {
        int r = ty + 4 * j;
        float acc = 0.f;
        #pragma unroll
        for (int s = 0; s < NSTATES; s++)
            acc += wv[s] * P[(size_t)s * HD * HD + (size_t)(d0 + r) * HD + e0 + tx];
        tile[r][tx] = acc;
    }
    __syncthreads();
    #pragma unroll
    for (int j = 0; j < 16; j++) {
        int er = ty + 4 * j;
        Mt[(size_t)(e0 + er) * HD + d0 + tx] = f2bf(tile[tx][er]);
    }
}

// ---------------- K4 fast: out = Xb @ Mt^T  (m97 structure) --------------------
// 128x128 tile, BK=64, linear LDS, global_load_lds width-16 staging.
__global__ __launch_bounds__(256) void k_gemm_fast(const short* __restrict__ Xb,
                                                   const short* __restrict__ Mt,
                                                   float* __restrict__ out) {
    int bid = blockIdx.x;
    int swz = (bid & 7) * (1024 >> 3) + (bid >> 3);   // 1024 blocks, %8==0 -> bijective
    int bm = swz >> 3, bn = swz & 7;
    int brow = bm * 128, bcol = bn * 128;

    __shared__ short As[128 * 64];  // [row][k] linear (global_load_lds order)
    __shared__ short Bs[128 * 64];  // [n][k]   linear

    int tid = threadIdx.x;
    int lane = tid & 63, wid = tid >> 6;
    int wr = wid >> 1, wc = wid & 1;

    f32x4 acc[4][4];
    #pragma unroll
    for (int m = 0; m < 4; m++)
        #pragma unroll
        for (int n = 0; n < 4; n++) acc[m][n] = (f32x4){0.f, 0.f, 0.f, 0.f};

    for (int kt = 0; kt < HD; kt += 64) {
        __syncthreads();   // previous tile fully consumed
        #pragma unroll
        for (int i = 0; i < 4; i++) {
            int chunk = tid + 256 * i;              // 16B chunk: row = chunk>>3
            int row = chunk >> 3, c8 = chunk & 7;
            const short* gA = Xb + (size_t)(brow + row) * HD + kt + c8 * 8;
            __builtin_amdgcn_global_load_lds(
                (const __attribute__((address_space(1))) void*)gA,
                (__attribute__((address_space(3))) void*)(As + (size_t)chunk * 8),
                16, 0, 0);
        }
        #pragma unroll
        for (int i = 0; i < 4; i++) {
            int chunk = tid + 256 * i;
            int row = chunk >> 3, c8 = chunk & 7;
            const short* gB = Mt + (size_t)(bcol + row) * HD + kt + c8 * 8;
            __builtin_amdgcn_global_load_lds(
                (const __attribute__((address_space(1))) void*)gB,
                (__attribute__((address_space(3))) void*)(Bs + (size_t)chunk * 8),
                16, 0, 0);
        }
        __syncthreads();   // compiler drains vmcnt(0) before this barrier
        #pragma unroll
        for (int kk = 0; kk < 2; kk++) {
            int kg = (lane >> 4) + kk * 4;          // 16B-chunk index along k
            short8 af[4], bfr[4];
            #pragma unroll
            for (int m = 0; m < 4; m++) {
                int row = wr * 64 + m * 16 + (lane & 15);
                af[m] = *reinterpret_cast<short8*>(&As[row * 64 + kg * 8]);
            }
            #pragma unroll
            for (int n = 0; n < 4; n++) {
                int row = wc * 64 + n * 16 + (lane & 15);
                bfr[n] = *reinterpret_cast<short8*>(&Bs[row * 64 + kg * 8]);
            }
            #pragma unroll
            for (int m = 0; m < 4; m++)
                #pragma unroll
                for (int n = 0; n < 4; n++)
                    acc[m][n] = __builtin_amdgcn_mfma_f32_16x16x32_bf16(af[m], bfr[n], acc[m][n], 0, 0, 0);
        }
    }
    // epilogue: C/D layout col=lane&15, row=(lane>>4)*4+j  [m89-verified]
    #pragma unroll
    for (int m = 0; m < 4; m++)
        #pragma unroll
        for (int n = 0; n < 4; n++)
            #pragma unroll
            for (int j = 0; j < 4; j++) {
                int r = brow + wr * 64 + m * 16 + (lane >> 4) * 4 + j;
                int c = bcol + wc * 64 + n * 16 + (lane & 15);
                out[(size_t)r * HD + c] = acc[m][n][j];
            }
}

// ---------------- K4 fallback: conversion-in-kernel (round-1 path) -------------
__global__ __launch_bounds__(256) void k_gemm_conv(const float* __restrict__ X,
                                                   const short* __restrict__ Mt,
                                                   float* __restrict__ out) {
    int bid = blockIdx.x;
    int swz = (bid & 7) * (1024 >> 3) + (bid >> 3);
    int bm = swz >> 3, bn = swz & 7;
    int brow = bm * 128, bcol = bn * 128;

    __shared__ short As[128 * 64];
    __shared__ short Bs[128 * 64];

    int tid = threadIdx.x;
    int lane = tid & 63, wid = tid >> 6;
    int wr = wid >> 1, wc = wid & 1;

    f32x4 acc[4][4];
    #pragma unroll
    for (int m = 0; m < 4; m++)
        #pragma unroll
        for (int n = 0; n < 4; n++) acc[m][n] = (f32x4){0.f, 0.f, 0.f, 0.f};

    for (int kt = 0; kt < HD; kt += 64) {
        __syncthreads();
        #pragma unroll
        for (int i = 0; i < 4; i++) {
            int chunk = tid + 256 * i;
            int row = chunk >> 3, c8 = chunk & 7;
            const float* src = X + (size_t)(brow + row) * HD + kt + c8 * 8;
            float4 f0 = *reinterpret_cast<const float4*>(src);
            float4 f1 = *reinterpret_cast<const float4*>(src + 4);
            short8 v;
            v[0] = f2bf(f0.x); v[1] = f2bf(f0.y); v[2] = f2bf(f0.z); v[3] = f2bf(f0.w);
            v[4] = f2bf(f1.x); v[5] = f2bf(f1.y); v[6] = f2bf(f1.z); v[7] = f2bf(f1.w);
            *reinterpret_cast<short8*>(&As[row * 64 + ((c8 ^ (row & 7)) * 8)]) = v;
        }
        #pragma unroll
        for (int i = 0; i < 4; i++) {
            int chunk = tid + 256 * i;
            int row = chunk >> 3, c8 = chunk & 7;
            short8 v = *reinterpret_cast<const short8*>(Mt + (size_t)(bcol + row) * HD + kt + c8 * 8);
            *reinterpret_cast<short8*>(&Bs[row * 64 + ((c8 ^ (row & 7)) * 8)]) = v;
        }
        __syncthreads();
        #pragma unroll
        for (int kk = 0; kk < 2; kk++) {
            int kg = (lane >> 4) + kk * 4;
            short8 af[4], bfr[4];
            #pragma unroll
            for (int m = 0; m < 4; m++) {
                int row = wr * 64 + m * 16 + (lane & 15);
                af[m] = *reinterpret_cast<short8*>(&As[row * 64 + ((kg ^ (row & 7)) * 8)]);
            }
            #pragma unroll
            for (int n = 0; n < 4; n++) {
                int row = wc * 64 + n * 16 + (lane & 15);
                bfr[n] = *reinterpret_cast<short8*>(&Bs[row * 64 + ((kg ^ (row & 7)) * 8)]);
            }
            #pragma unroll
            for (int m = 0; m < 4; m++)
                #pragma unroll
                for (int n = 0; n < 4; n++)
                    acc[m][n] = __builtin_amdgcn_mfma_f32_16x16x32_bf16(af[m], bfr[n], acc[m][n], 0, 0, 0);
        }
    }
    #pragma unroll
    for (int m = 0; m < 4; m++)
        #pragma unroll
        for (int n = 0; n < 4; n++)
            #pragma unroll
            for (int j = 0; j < 4; j++) {
                int r = brow + wr * 64 + m * 16 + (lane >> 4) * 4 + j;
                int c = bcol + wc * 64 + n * 16 + (lane & 15);
                out[(size_t)r * HD + c] = acc[m][n][j];
            }
}

extern "C" void kernel_launch(void* const* d_in, const int* in_sizes, int n_in,
                              void* d_out, int out_size, void* d_ws, size_t ws_size,
                              hipStream_t stream) {
    const float* X  = (const float*)d_in[0];  // [16384,1024]
    const float* AR = (const float*)d_in[1];
    const float* AI = (const float*)d_in[2];
    const float* H  = (const float*)d_in[3];
    const float* P  = (const float*)d_in[4];  // [8,1024,1024]
    float* out = (float*)d_out;

    char* ws = (char*)d_ws;
    float* w  = (float*)ws;                       // 32 KB
    short* Mt = (short*)(ws + 32768);             // 2 MB  (bf16 M^T)
    short* Xb = (short*)(ws + 32768 + 2097152);   // 32 MB (bf16 X)
    const size_t needFast = 32768 + 2097152 + (size_t)NBATCH * HD * 2;

    k_amps<<<1, 1024, 0, stream>>>(AR, AI, H, out, w);
    k_project_t<<<256, 256, 0, stream>>>(P, w, Mt);
    if (ws_size >= needFast) {
        k_castX<<<(NBATCH * HD) / (256 * 8), 256, 0, stream>>>(X, Xb);
        k_gemm_fast<<<(NBATCH / 128) * (HD / 128), 256, 0, stream>>>(Xb, Mt, out);
    } else {
        k_gemm_conv<<<(NBATCH / 128) * (HD / 128), 256, 0, stream>>>(X, Mt, out);
    }
}

// Round 3
// 94.147 us; speedup vs baseline: 1.1480x; 1.1480x over previous
//
#include <hip/hip_runtime.h>
#include <hip/hip_bf16.h>

#define NSTATES 8
#define HD      1024
#define NBATCH  16384
#define NT      16      // K-tiles of 64

// output layout (flat fp32, return order)
#define OUT_MEAS 0
#define OUT_CP   16777216
#define OUT_ENT  16777224
#define OUT_COH  16777225
#define OUT_AD   16777226
#define OUT_PH   16785418

typedef __attribute__((ext_vector_type(8))) short short8;
typedef __attribute__((ext_vector_type(4))) float f32x4;

__device__ __forceinline__ short f2bf(float f) {
    union { float f; unsigned u; } x; x.f = f;
    unsigned r = x.u + 0x7fffu + ((x.u >> 16) & 1u);  // RNE
    return (short)(r >> 16);
}

// block-wide sum; valid result on thread 0 only. red = shared float[16].
__device__ __forceinline__ float blockReduceTo0(float v, float* red) {
    #pragma unroll
    for (int o = 32; o > 0; o >>= 1) v += __shfl_down(v, o, 64);
    int lane = threadIdx.x & 63, wid = threadIdx.x >> 6;
    __syncthreads();
    if (lane == 0) red[wid] = v;
    __syncthreads();
    float r = 0.f;
    if (wid == 0) {
        r = (lane < 16) ? red[lane] : 0.f;
        #pragma unroll
        for (int o = 8; o > 0; o >>= 1) r += __shfl_down(r, o, 64);
    }
    return r;
}

// ---------------- K1: amplitude pipeline (1 block, 1024 threads) ----------------
__global__ __launch_bounds__(1024) void k_amps(const float* __restrict__ AR,
                                               const float* __restrict__ AI,
                                               const float* __restrict__ H,
                                               float* __restrict__ out,
                                               float* __restrict__ w) {
    __shared__ float red[16];
    __shared__ float norms[NSTATES];
    __shared__ float Ur[NSTATES][NSTATES], Ui[NSTATES][NSTATES];

    const int d = threadIdx.x;
    float arv[NSTATES], aiv[NSTATES];
    #pragma unroll
    for (int s = 0; s < NSTATES; s++) {
        arv[s] = AR[s * HD + d];
        aiv[s] = AI[s * HD + d];
    }
    #pragma unroll
    for (int s = 0; s < NSTATES; s++) {
        float r = blockReduceTo0(arv[s] * arv[s] + aiv[s] * aiv[s], red);
        if (threadIdx.x == 0) norms[s] = r;
    }
    if (threadIdx.x == 0) {
        float A[8][8], A2[8][8], A3[8][8];
        for (int i = 0; i < 8; i++)
            for (int j = 0; j < 8; j++)
                A[i][j] = 0.5f * (H[i * 8 + j] + H[j * 8 + i]) * 0.01f;  // DT/PLANCK
        for (int i = 0; i < 8; i++)
            for (int j = 0; j < 8; j++) {
                float acc = 0.f;
                for (int k = 0; k < 8; k++) acc += A[i][k] * A[k][j];
                A2[i][j] = acc;
            }
        for (int i = 0; i < 8; i++)
            for (int j = 0; j < 8; j++) {
                float acc = 0.f;
                for (int k = 0; k < 8; k++) acc += A2[i][k] * A[k][j];
                A3[i][j] = acc;
            }
        for (int i = 0; i < 8; i++)
            for (int j = 0; j < 8; j++) {
                Ur[i][j] = ((i == j) ? 1.f : 0.f) - 0.5f * A2[i][j];     // cos(A)
                Ui[i][j] = -(A[i][j] - A3[i][j] * (1.f / 6.f));          // -sin(A)
            }
    }
    __syncthreads();

    #pragma unroll
    for (int s = 0; s < NSTATES; s++) {
        float inv = 1.0f / sqrtf(norms[s] + 1e-8f);
        arv[s] *= inv;
        aiv[s] *= inv;
    }
    float nr[NSTATES], ni[NSTATES];
    #pragma unroll
    for (int s = 0; s < NSTATES; s++) {
        float xr = 0.f, xi = 0.f;
        #pragma unroll
        for (int t = 0; t < NSTATES; t++) {
            float ur = Ur[s][t], ui = Ui[s][t];
            xr += ur * arv[t] - ui * aiv[t];
            xi += ur * aiv[t] + ui * arv[t];
        }
        nr[s] = xr; ni[s] = xi;
    }
    float dist[NSTATES], csum = 0.f, sabs = 0.f;
    #pragma unroll
    for (int s = 0; s < NSTATES; s++) {
        dist[s] = nr[s] * nr[s] + ni[s] * ni[s];
        csum += dist[s];
        sabs += sqrtf(dist[s]);
    }
    #pragma unroll
    for (int s = 0; s < NSTATES; s++) {
        out[OUT_AD + s * HD + d] = dist[s];
        out[OUT_PH + s * HD + d] = atan2f(ni[s], nr[s]);
        w[s * HD + d] = nr[s];
    }
    float cinv = 1.0f / (csum + 1e-8f);
    #pragma unroll
    for (int s = 0; s < NSTATES; s++) {
        float r = blockReduceTo0(dist[s] * cinv, red);
        if (threadIdx.x == 0) out[OUT_CP + s] = r * (1.0f / HD);
    }
    float lam = blockReduceTo0(csum, red);
    float sa  = blockReduceTo0(sabs, red);
    if (threadIdx.x == 0) {
        out[OUT_ENT] = -(lam * logf(lam + 1e-12f));
        out[OUT_COH] = sa * sa - lam;
    }
}

// ---------------- K2: X (fp32) -> Xb (bf16), vectorized ----------------
__global__ __launch_bounds__(256) void k_castX(const float* __restrict__ X,
                                               short* __restrict__ Xb) {
    int idx = blockIdx.x * 256 + threadIdx.x;
    const float* src = X + (size_t)idx * 8;
    float4 f0 = *reinterpret_cast<const float4*>(src);
    float4 f1 = *reinterpret_cast<const float4*>(src + 4);
    short8 v;
    v[0] = f2bf(f0.x); v[1] = f2bf(f0.y); v[2] = f2bf(f0.z); v[3] = f2bf(f0.w);
    v[4] = f2bf(f1.x); v[5] = f2bf(f1.y); v[6] = f2bf(f1.z); v[7] = f2bf(f1.w);
    *reinterpret_cast<short8*>(Xb + (size_t)idx * 8) = v;
}

// ------- K3: fused project + transpose: Mt[e,d] = bf16( sum_s w[s,e]*P[s,d,e] ) -
__global__ __launch_bounds__(256) void k_project_t(const float* __restrict__ P,
                                                   const float* __restrict__ w,
                                                   short* __restrict__ Mt) {
    __shared__ float tile[64][65];
    int d0 = (blockIdx.x >> 4) * 64;
    int e0 = (blockIdx.x & 15) * 64;
    int tx = threadIdx.x & 63, ty = threadIdx.x >> 6;
    float wv[NSTATES];
    #pragma unroll
    for (int s = 0; s < NSTATES; s++) wv[s] = w[s * HD + e0 + tx];
    #pragma unroll
    for (int j = 0; j < 16; j++) {
        int r = ty + 4 * j;
        float acc = 0.f;
        #pragma unroll
        for (int s = 0; s < NSTATES; s++)
            acc += wv[s] * P[(size_t)s * HD * HD + (size_t)(d0 + r) * HD + e0 + tx];
        tile[r][tx] = acc;
    }
    __syncthreads();
    #pragma unroll
    for (int j = 0; j < 16; j++) {
        int er = ty + 4 * j;
        Mt[(size_t)(e0 + er) * HD + d0 + tx] = f2bf(tile[tx][er]);
    }
}

// ---------------- K4: out = Xb @ Mt^T  -- 256^2 8-phase template ----------------
// 512 threads = 8 waves (2M x 4N); BM=BN=256, BK=64; LDS 128 KiB double-buffered.
// T1 XCD swizzle, T2 LDS XOR-swizzle (both-sides), T3+T4 counted vmcnt, T5 setprio.

__device__ __forceinline__ void stage_half(const short* __restrict__ srcBase,
                                           int rowbase, int h, int t2,
                                           short* dst, const int* aoff,
                                           const int* ldsoff) {
    #pragma unroll
    for (int i = 0; i < 2; i++) {
        const short* g = srcBase + (size_t)(rowbase + h * 128) * HD + t2 * 64 + aoff[i];
        __builtin_amdgcn_global_load_lds(
            (const __attribute__((address_space(1))) void*)g,
            (__attribute__((address_space(3))) void*)(dst + h * 8192 + ldsoff[i]),
            16, 0, 0);
    }
}

#define LOAD_A(q)                                                              \
    _Pragma("unroll") for (int mf = 0; mf < 4; mf++)                           \
    _Pragma("unroll") for (int kk = 0; kk < 2; kk++)                           \
        af[mf][kk] = *reinterpret_cast<const short8*>(                         \
            &As[cur][(wrbase + (q) * 64 + mf * 16 + ln15) * 64 + kx[kk]]);

#define LOAD_B(nh)                                                             \
    _Pragma("unroll") for (int nf = 0; nf < 2; nf++)                           \
    _Pragma("unroll") for (int kk = 0; kk < 2; kk++)                           \
        bf[nf][kk] = *reinterpret_cast<const short8*>(                         \
            &Bs[cur][(wnbase + (nh) * 32 + nf * 16 + ln15) * 64 + kx[kk]]);

#define MFMA_Q(q, nh)                                                          \
    _Pragma("unroll") for (int mf = 0; mf < 4; mf++)                           \
    _Pragma("unroll") for (int nf = 0; nf < 2; nf++)                           \
    _Pragma("unroll") for (int kk = 0; kk < 2; kk++)                           \
        acc[(q) * 4 + mf][(nh) * 2 + nf] =                                     \
            __builtin_amdgcn_mfma_f32_16x16x32_bf16(                           \
                af[mf][kk], bf[nf][kk], acc[(q) * 4 + mf][(nh) * 2 + nf], 0, 0, 0);

#define PHASE_MID()                                                            \
    __builtin_amdgcn_s_barrier();                                              \
    asm volatile("s_waitcnt lgkmcnt(0)" ::: "memory");                         \
    __builtin_amdgcn_sched_barrier(0);                                         \
    __builtin_amdgcn_s_setprio(1);

#define PHASE_END()                                                            \
    __builtin_amdgcn_s_setprio(0);                                             \
    __builtin_amdgcn_s_barrier();

__global__ __launch_bounds__(512, 1) void k_gemm_8p(const short* __restrict__ Xb,
                                                    const short* __restrict__ Mt,
                                                    float* __restrict__ out) {
    __shared__ short As[2][256 * 64];   // 64 KiB, [buf][row][kchunk swizzled]
    __shared__ short Bs[2][256 * 64];   // 64 KiB

    const int bid = blockIdx.x;                       // 256 blocks (64 bm x 4 bn)
    const int swz = (bid & 7) * 32 + (bid >> 3);      // XCD-contiguous, bijective
    const int brow = (swz >> 2) * 256;
    const int bcol = (swz & 3) * 256;

    const int tid  = threadIdx.x;
    const int lane = tid & 63, wid = tid >> 6;
    const int wr = wid >> 2, wn = wid & 3;            // 2M x 4N waves
    const int ln15 = lane & 15, l16 = lane >> 4;
    const int wrbase = wr * 128;                      // A rows of this wave
    const int wnbase = wn * 64;                       // B rows (out cols) of this wave

    // ds_read swizzled k-chunk offsets (shorts): chunk = kg ^ (row&7), row&7 == ln15&7
    int kx[2];
    kx[0] = ((l16 + 0) ^ (ln15 & 7)) * 8;
    kx[1] = ((l16 + 4) ^ (ln15 & 7)) * 8;

    // staging offsets: LDS linear dest, inverse-swizzled global source
    int aoff[2], ldsoff[2];
    #pragma unroll
    for (int i = 0; i < 2; i++) {
        int c = tid + 512 * i;
        int row = c >> 3, kc = c & 7;
        aoff[i]   = row * HD + ((kc ^ (row & 7)) * 8);
        ldsoff[i] = c * 8;
    }

    short* A0 = &As[0][0]; short* A1 = &As[1][0];
    short* B0 = &Bs[0][0]; short* B1 = &Bs[1][0];

    f32x4 acc[8][4];
    #pragma unroll
    for (int m = 0; m < 8; m++)
        #pragma unroll
        for (int n = 0; n < 4; n++) acc[m][n] = (f32x4){0.f, 0.f, 0.f, 0.f};

    // prologue: tile0 full (8 loads) + tile1 A-lo,A-hi,B-lo (6 loads)
    stage_half(Xb, brow, 0, 0, A0, aoff, ldsoff);
    stage_half(Xb, brow, 1, 0, A0, aoff, ldsoff);
    stage_half(Mt, bcol, 0, 0, B0, aoff, ldsoff);
    stage_half(Mt, bcol, 1, 0, B0, aoff, ldsoff);
    stage_half(Xb, brow, 0, 1, A1, aoff, ldsoff);
    stage_half(Xb, brow, 1, 1, A1, aoff, ldsoff);
    stage_half(Mt, bcol, 0, 1, B1, aoff, ldsoff);
    asm volatile("s_waitcnt vmcnt(6)" ::: "memory");  // tile0's 8 loads landed
    __builtin_amdgcn_s_barrier();

    short8 af[4][2], bf[2][2];

    #pragma unroll 1
    for (int t = 0; t < NT; t++) {
        const int cur = t & 1;
        short* Acur = cur ? A1 : A0;  (void)Acur;
        short* Anext = cur ? A0 : A1;
        short* Bnext = cur ? B0 : B1;
        short* Bnn   = cur ? B1 : B0;  // buf of t+1

        // ---- ph1: quadrant (A-q0, B-lo); stage H(t+1, B-hi)
        LOAD_A(0); LOAD_B(0);
        if (t + 1 < NT) stage_half(Mt, bcol, 1, t + 1, Bnn, aoff, ldsoff);
        PHASE_MID();
        MFMA_Q(0, 0);
        PHASE_END();

        // ---- ph2: (A-q0, B-hi)
        LOAD_B(1);
        PHASE_MID();
        MFMA_Q(0, 1);
        PHASE_END();

        // ---- ph3: (A-q1, B-lo)
        LOAD_A(1); LOAD_B(0);
        PHASE_MID();
        MFMA_Q(1, 0);
        PHASE_END();

        // ---- ph4: (A-q1, B-hi); stage H(t+2, A-lo/A-hi/B-lo); counted vmcnt
        LOAD_B(1);
        if (t + 2 < NT) {
            stage_half(Xb, brow, 0, t + 2, Anext, aoff, ldsoff);
            stage_half(Xb, brow, 1, t + 2, Anext, aoff, ldsoff);
            stage_half(Mt, bcol, 0, t + 2, Bnext, aoff, ldsoff);
        }
        PHASE_MID();
        MFMA_Q(1, 1);
        __builtin_amdgcn_s_setprio(0);
        if (t < NT - 2)       asm volatile("s_waitcnt vmcnt(6)" ::: "memory");
        else if (t == NT - 2) asm volatile("s_waitcnt vmcnt(0)" ::: "memory");
        __builtin_amdgcn_s_barrier();
    }

    // epilogue: C/D layout col=lane&15, row=(lane>>4)*4+j  [m89-verified]
    #pragma unroll
    for (int m = 0; m < 8; m++)
        #pragma unroll
        for (int n = 0; n < 4; n++)
            #pragma unroll
            for (int j = 0; j < 4; j++) {
                int r = brow + wrbase + m * 16 + l16 * 4 + j;
                int c = bcol + wnbase + n * 16 + ln15;
                out[(size_t)r * HD + c] = acc[m][n][j];
            }
}

extern "C" void kernel_launch(void* const* d_in, const int* in_sizes, int n_in,
                              void* d_out, int out_size, void* d_ws, size_t ws_size,
                              hipStream_t stream) {
    const float* X  = (const float*)d_in[0];  // [16384,1024]
    const float* AR = (const float*)d_in[1];
    const float* AI = (const float*)d_in[2];
    const float* H  = (const float*)d_in[3];
    const float* P  = (const float*)d_in[4];  // [8,1024,1024]
    float* out = (float*)d_out;

    char* ws = (char*)d_ws;
    float* w  = (float*)ws;                       // 32 KB
    short* Mt = (short*)(ws + 32768);             // 2 MB  (bf16 M^T)
    short* Xb = (short*)(ws + 32768 + 2097152);   // 32 MB (bf16 X)

    k_amps<<<1, 1024, 0, stream>>>(AR, AI, H, out, w);
    k_project_t<<<256, 256, 0, stream>>>(P, w, Mt);
    k_castX<<<(NBATCH * HD) / (256 * 8), 256, 0, stream>>>(X, Xb);
    k_gemm_8p<<<(NBATCH / 256) * (HD / 256), 512, 0, stream>>>(Xb, Mt, out);
}

// Round 4
// 79.982 us; speedup vs baseline: 1.3513x; 1.1771x over previous
//
#include <hip/hip_runtime.h>
#include <hip/hip_bf16.h>

#define NSTATES 8
#define HD      1024
#define NBATCH  16384
#define NT      16      // K-tiles of 64

// output layout (flat fp32, return order)
#define OUT_MEAS 0
#define OUT_CP   16777216
#define OUT_ENT  16777224
#define OUT_COH  16777225
#define OUT_AD   16777226
#define OUT_PH   16785418

typedef __attribute__((ext_vector_type(8))) short short8;
typedef __attribute__((ext_vector_type(4))) float f32x4;

__device__ __forceinline__ short f2bf(float f) {
    union { float f; unsigned u; } x; x.f = f;
    unsigned r = x.u + 0x7fffu + ((x.u >> 16) & 1u);  // RNE
    return (short)(r >> 16);
}

// ---------------- K1: amplitude pipeline (1 block, 1024 threads) ----------------
// Batched reductions: one LDS round for the 8 norms, one for the 10 outputs.
__global__ __launch_bounds__(1024) void k_amps(const float* __restrict__ AR,
                                               const float* __restrict__ AI,
                                               const float* __restrict__ H,
                                               float* __restrict__ out,
                                               float* __restrict__ w) {
    __shared__ float redA[16 * NSTATES];       // wave partials: norms
    __shared__ float redB[16 * 10];            // wave partials: cp[8], lam, sa
    __shared__ float norms[NSTATES];
    __shared__ float sA[8][8], sA2[8][8], sA3[8][8];
    __shared__ float Ur[8][8], Ui[8][8];
    __shared__ float lamsa[2];

    const int tid = threadIdx.x;
    const int lane = tid & 63, wid = tid >> 6;
    const int d = tid;

    float arv[NSTATES], aiv[NSTATES];
    #pragma unroll
    for (int s = 0; s < NSTATES; s++) {
        arv[s] = AR[s * HD + d];
        aiv[s] = AI[s * HD + d];
    }
    // --- batched norm reduction ---
    float p[NSTATES];
    #pragma unroll
    for (int s = 0; s < NSTATES; s++) p[s] = arv[s] * arv[s] + aiv[s] * aiv[s];
    #pragma unroll
    for (int s = 0; s < NSTATES; s++)
        #pragma unroll
        for (int o = 32; o > 0; o >>= 1) p[s] += __shfl_down(p[s], o, 64);
    if (lane == 0)
        #pragma unroll
        for (int s = 0; s < NSTATES; s++) redA[wid * NSTATES + s] = p[s];
    // --- expm prep (parallel over 64 threads) ---
    if (tid < 64) {
        int i = tid >> 3, j = tid & 7;
        sA[i][j] = 0.5f * (H[i * 8 + j] + H[j * 8 + i]) * 0.01f;  // DT/PLANCK
    }
    __syncthreads();
    if (tid < 8) {
        float acc = 0.f;
        #pragma unroll
        for (int v = 0; v < 16; v++) acc += redA[v * NSTATES + tid];
        norms[tid] = acc;
    }
    if (tid < 64) {
        int i = tid >> 3, j = tid & 7;
        float acc = 0.f;
        #pragma unroll
        for (int k = 0; k < 8; k++) acc += sA[i][k] * sA[k][j];
        sA2[i][j] = acc;
    }
    __syncthreads();
    if (tid < 64) {
        int i = tid >> 3, j = tid & 7;
        float acc = 0.f;
        #pragma unroll
        for (int k = 0; k < 8; k++) acc += sA2[i][k] * sA[k][j];
        sA3[i][j] = acc;
        Ur[i][j] = ((i == j) ? 1.f : 0.f) - 0.5f * sA2[i][j];   // cos(A)
        Ui[i][j] = -(sA[i][j] - sA3[i][j] * (1.f / 6.f));       // -sin(A)
    }
    __syncthreads();

    #pragma unroll
    for (int s = 0; s < NSTATES; s++) {
        float inv = 1.0f / sqrtf(norms[s] + 1e-8f);
        arv[s] *= inv;
        aiv[s] *= inv;
    }
    float nr[NSTATES], ni[NSTATES];
    #pragma unroll
    for (int s = 0; s < NSTATES; s++) {
        float xr = 0.f, xi = 0.f;
        #pragma unroll
        for (int t = 0; t < NSTATES; t++) {
            float ur = Ur[s][t], ui = Ui[s][t];
            xr += ur * arv[t] - ui * aiv[t];
            xi += ur * aiv[t] + ui * arv[t];
        }
        nr[s] = xr; ni[s] = xi;
    }
    float dist[NSTATES], csum = 0.f, sabs = 0.f;
    #pragma unroll
    for (int s = 0; s < NSTATES; s++) {
        dist[s] = nr[s] * nr[s] + ni[s] * ni[s];
        csum += dist[s];
        sabs += sqrtf(dist[s]);
    }
    #pragma unroll
    for (int s = 0; s < NSTATES; s++) {
        out[OUT_AD + s * HD + d] = dist[s];
        out[OUT_PH + s * HD + d] = atan2f(ni[s], nr[s]);
        w[s * HD + d] = nr[s];
    }
    // --- batched final reduction: cp[8], lam, sa ---
    float cinv = 1.0f / (csum + 1e-8f);
    float q[10];
    #pragma unroll
    for (int s = 0; s < NSTATES; s++) q[s] = dist[s] * cinv;
    q[8] = csum; q[9] = sabs;
    #pragma unroll
    for (int v = 0; v < 10; v++)
        #pragma unroll
        for (int o = 32; o > 0; o >>= 1) q[v] += __shfl_down(q[v], o, 64);
    if (lane == 0)
        #pragma unroll
        for (int v = 0; v < 10; v++) redB[wid * 10 + v] = q[v];
    __syncthreads();
    if (tid < 10) {
        float acc = 0.f;
        #pragma unroll
        for (int v = 0; v < 16; v++) acc += redB[v * 10 + tid];
        if (tid < 8)       out[OUT_CP + tid] = acc * (1.0f / HD);
        else               lamsa[tid - 8] = acc;
    }
    __syncthreads();
    if (tid == 0) {
        float lam = lamsa[0], sa = lamsa[1];
        out[OUT_ENT] = -(lam * logf(lam + 1e-12f));
        out[OUT_COH] = sa * sa - lam;
    }
}

// ---------------- K2: X (fp32) -> Xb (bf16), vectorized ----------------
__global__ __launch_bounds__(256) void k_castX(const float* __restrict__ X,
                                               short* __restrict__ Xb) {
    int idx = blockIdx.x * 256 + threadIdx.x;
    const float* src = X + (size_t)idx * 8;
    float4 f0 = *reinterpret_cast<const float4*>(src);
    float4 f1 = *reinterpret_cast<const float4*>(src + 4);
    short8 v;
    v[0] = f2bf(f0.x); v[1] = f2bf(f0.y); v[2] = f2bf(f0.z); v[3] = f2bf(f0.w);
    v[4] = f2bf(f1.x); v[5] = f2bf(f1.y); v[6] = f2bf(f1.z); v[7] = f2bf(f1.w);
    *reinterpret_cast<short8*>(Xb + (size_t)idx * 8) = v;
}

// ------- K3: fused project + transpose: Mt[e,d] = bf16( sum_s w[s,e]*P[s,d,e] ) -
__global__ __launch_bounds__(256) void k_project_t(const float* __restrict__ P,
                                                   const float* __restrict__ w,
                                                   short* __restrict__ Mt) {
    __shared__ float tile[64][65];
    int d0 = (blockIdx.x >> 4) * 64;
    int e0 = (blockIdx.x & 15) * 64;
    int tx = threadIdx.x & 63, ty = threadIdx.x >> 6;
    float wv[NSTATES];
    #pragma unroll
    for (int s = 0; s < NSTATES; s++) wv[s] = w[s * HD + e0 + tx];
    #pragma unroll
    for (int j = 0; j < 16; j++) {
        int r = ty + 4 * j;
        float acc = 0.f;
        #pragma unroll
        for (int s = 0; s < NSTATES; s++)
            acc += wv[s] * P[(size_t)s * HD * HD + (size_t)(d0 + r) * HD + e0 + tx];
        tile[r][tx] = acc;
    }
    __syncthreads();
    #pragma unroll
    for (int j = 0; j < 16; j++) {
        int er = ty + 4 * j;
        Mt[(size_t)(e0 + er) * HD + d0 + tx] = f2bf(tile[tx][er]);
    }
}

// ---------------- K4: out = Xb @ Mt^T  -- 256^2 quadrant-phase template --------
// 512 threads = 8 waves (2M x 4N within each 128x128 quadrant). Phase = (A-half,
// B-half) of the C quadrant, order (0,0),(0,1),(1,1),(1,0). Each phase stages one
// half-tile; counted vmcnt(4) once per K-tile. T1 XCD swizzle + T2 both-sides
// LDS XOR-swizzle + T5 setprio.

__device__ __forceinline__ void stage_half(const short* __restrict__ srcBase,
                                           int rowbase, int h, int t2,
                                           short* dst, const int* aoff,
                                           const int* ldsoff) {
    #pragma unroll
    for (int i = 0; i < 2; i++) {
        const short* g = srcBase + (size_t)(rowbase + h * 128) * HD + t2 * 64 + aoff[i];
        __builtin_amdgcn_global_load_lds(
            (const __attribute__((address_space(1))) void*)g,
            (__attribute__((address_space(3))) void*)(dst + h * 8192 + ldsoff[i]),
            16, 0, 0);
    }
}

#define LOAD_A(qa)                                                             \
    _Pragma("unroll") for (int mf = 0; mf < 4; mf++)                           \
    _Pragma("unroll") for (int kk = 0; kk < 2; kk++)                           \
        af[mf][kk] = *reinterpret_cast<const short8*>(                         \
            &Acur[((qa) * 128 + wr64 + mf * 16 + ln15) * 64 + kx[kk]]);

#define LOAD_B(qb)                                                             \
    _Pragma("unroll") for (int nf = 0; nf < 2; nf++)                           \
    _Pragma("unroll") for (int kk = 0; kk < 2; kk++)                           \
        bf[nf][kk] = *reinterpret_cast<const short8*>(                         \
            &Bcur[((qb) * 128 + wn32 + nf * 16 + ln15) * 64 + kx[kk]]);

#define MFMA_P(qa, qb)                                                         \
    _Pragma("unroll") for (int mf = 0; mf < 4; mf++)                           \
    _Pragma("unroll") for (int nf = 0; nf < 2; nf++)                           \
    _Pragma("unroll") for (int kk = 0; kk < 2; kk++)                           \
        acc[(qa) * 4 + mf][(qb) * 2 + nf] =                                    \
            __builtin_amdgcn_mfma_f32_16x16x32_bf16(                           \
                af[mf][kk], bf[nf][kk], acc[(qa) * 4 + mf][(qb) * 2 + nf], 0, 0, 0);

#define PHASE_MID()                                                            \
    __builtin_amdgcn_s_barrier();                                              \
    __builtin_amdgcn_s_setprio(1);

#define PHASE_END()                                                            \
    __builtin_amdgcn_s_setprio(0);                                             \
    __builtin_amdgcn_s_barrier();

__global__ __launch_bounds__(512, 1) void k_gemm_8p(const short* __restrict__ Xb,
                                                    const short* __restrict__ Mt,
                                                    float* __restrict__ out) {
    __shared__ short As[2][256 * 64];   // 64 KiB: [buf][half*128+row][kchunk]
    __shared__ short Bs[2][256 * 64];   // 64 KiB

    const int bid = blockIdx.x;                       // 256 blocks (64 bm x 4 bn)
    const int swz = (bid & 7) * 32 + (bid >> 3);      // XCD-contiguous, bijective
    const int brow = (swz >> 2) * 256;
    const int bcol = (swz & 3) * 256;

    const int tid  = threadIdx.x;
    const int lane = tid & 63, wid = tid >> 6;
    const int wr = wid >> 2, wn = wid & 3;            // 2M x 4N within quadrant
    const int ln15 = lane & 15, l16 = lane >> 4;
    const int wr64 = wr * 64;                         // wave rows within quadrant
    const int wn32 = wn * 32;                         // wave cols within quadrant

    // ds_read swizzled k-chunk offsets (shorts): chunk = kg ^ (row&7); row&7==ln15&7
    int kx[2];
    kx[0] = ((l16 + 0) ^ (ln15 & 7)) * 8;
    kx[1] = ((l16 + 4) ^ (ln15 & 7)) * 8;

    // staging offsets: LDS linear dest, inverse-swizzled global source (128-row half)
    int aoff[2], ldsoff[2];
    #pragma unroll
    for (int i = 0; i < 2; i++) {
        int c = tid + 512 * i;
        int row = c >> 3, kc = c & 7;
        aoff[i]   = row * HD + ((kc ^ (row & 7)) * 8);
        ldsoff[i] = c * 8;
    }

    short* A0 = &As[0][0]; short* A1b = &As[1][0];
    short* B0 = &Bs[0][0]; short* B1b = &Bs[1][0];

    f32x4 acc[8][4];
    #pragma unroll
    for (int m = 0; m < 8; m++)
        #pragma unroll
        for (int n = 0; n < 4; n++) acc[m][n] = (f32x4){0.f, 0.f, 0.f, 0.f};

    // prologue: tile0 (4 halves) + A-lo(1) + B-hi(1)  [12 loads total]
    stage_half(Xb, brow, 0, 0, A0, aoff, ldsoff);
    stage_half(Xb, brow, 1, 0, A0, aoff, ldsoff);
    stage_half(Mt, bcol, 0, 0, B0, aoff, ldsoff);
    stage_half(Mt, bcol, 1, 0, B0, aoff, ldsoff);
    stage_half(Xb, brow, 0, 1, A1b, aoff, ldsoff);
    stage_half(Mt, bcol, 1, 1, B1b, aoff, ldsoff);
    asm volatile("s_waitcnt vmcnt(4)" ::: "memory");  // tile0's 8 loads landed
    __builtin_amdgcn_s_barrier();

    short8 af[4][2], bf[2][2];

    #pragma unroll 1
    for (int t = 0; t < NT; t++) {
        const int cur = t & 1;
        short* Acur  = cur ? A1b : A0;
        short* Bcur  = cur ? B1b : B0;
        short* Anext = cur ? A0 : A1b;   // buf of t+1
        short* Bnext = cur ? B0 : B1b;

        // ---- ph1: quadrant (0,0); stage A-hi(t+1) (its slot freed end of t-1)
        LOAD_A(0); LOAD_B(0);
        if (t + 1 < NT) stage_half(Xb, brow, 1, t + 1, Anext, aoff, ldsoff);
        PHASE_MID();
        MFMA_P(0, 0);
        PHASE_END();

        // ---- ph2: quadrant (0,1); stage B-lo(t+1); reuse af
        LOAD_B(1);
        if (t + 1 < NT) stage_half(Mt, bcol, 0, t + 1, Bnext, aoff, ldsoff);
        PHASE_MID();
        MFMA_P(0, 1);
        PHASE_END();

        // ---- ph3: quadrant (1,1); stage A-lo(t+2) into cur (A-lo dead after ph2)
        LOAD_A(1);
        if (t + 2 < NT) stage_half(Xb, brow, 0, t + 2, Acur, aoff, ldsoff);
        PHASE_MID();
        MFMA_P(1, 1);
        PHASE_END();

        // ---- ph4: quadrant (1,0); stage B-hi(t+2) into cur (B-hi dead after ph3)
        LOAD_B(0);
        if (t + 2 < NT) stage_half(Mt, bcol, 1, t + 2, Bcur, aoff, ldsoff);
        PHASE_MID();
        MFMA_P(1, 0);
        __builtin_amdgcn_s_setprio(0);
        // counted wait: oldest 8 of 12 in flight = all of tile t+1
        if (t < NT - 2)       asm volatile("s_waitcnt vmcnt(4)" ::: "memory");
        else if (t == NT - 2) asm volatile("s_waitcnt vmcnt(0)" ::: "memory");
        __builtin_amdgcn_s_barrier();
    }

    // epilogue: C/D layout col=lane&15, row=(lane>>4)*4+j  [m89-verified]
    #pragma unroll
    for (int qa = 0; qa < 2; qa++)
        #pragma unroll
        for (int mf = 0; mf < 4; mf++)
            #pragma unroll
            for (int qb = 0; qb < 2; qb++)
                #pragma unroll
                for (int nf = 0; nf < 2; nf++)
                    #pragma unroll
                    for (int j = 0; j < 4; j++) {
                        int r = brow + qa * 128 + wr64 + mf * 16 + l16 * 4 + j;
                        int c = bcol + qb * 128 + wn32 + nf * 16 + ln15;
                        out[(size_t)r * HD + c] = acc[qa * 4 + mf][qb * 2 + nf][j];
                    }
}

extern "C" void kernel_launch(void* const* d_in, const int* in_sizes, int n_in,
                              void* d_out, int out_size, void* d_ws, size_t ws_size,
                              hipStream_t stream) {
    const float* X  = (const float*)d_in[0];  // [16384,1024]
    const float* AR = (const float*)d_in[1];
    const float* AI = (const float*)d_in[2];
    const float* H  = (const float*)d_in[3];
    const float* P  = (const float*)d_in[4];  // [8,1024,1024]
    float* out = (float*)d_out;

    char* ws = (char*)d_ws;
    float* w  = (float*)ws;                       // 32 KB
    short* Mt = (short*)(ws + 32768);             // 2 MB  (bf16 M^T)
    short* Xb = (short*)(ws + 32768 + 2097152);   // 32 MB (bf16 X)

    k_amps<<<1, 1024, 0, stream>>>(AR, AI, H, out, w);
    k_project_t<<<256, 256, 0, stream>>>(P, w, Mt);
    k_castX<<<(NBATCH * HD) / (256 * 8), 256, 0, stream>>>(X, Xb);
    k_gemm_8p<<<(NBATCH / 256) * (HD / 256), 512, 0, stream>>>(Xb, Mt, out);
}

// Round 5
// 76.428 us; speedup vs baseline: 1.4142x; 1.0465x over previous
//
#include <hip/hip_runtime.h>
#include <hip/hip_bf16.h>

#define NSTATES 8
#define HD      1024
#define NBATCH  16384
#define NT      16      // K-tiles of 64

// output layout (flat fp32, return order)
#define OUT_MEAS 0
#define OUT_CP   16777216
#define OUT_ENT  16777224
#define OUT_COH  16777225
#define OUT_AD   16777226
#define OUT_PH   16785418

typedef __attribute__((ext_vector_type(8))) short short8;
typedef __attribute__((ext_vector_type(4))) float f32x4;

__device__ __forceinline__ short f2bf(float f) {
    union { float f; unsigned u; } x; x.f = f;
    unsigned r = x.u + 0x7fffu + ((x.u >> 16) & 1u);  // RNE
    return (short)(r >> 16);
}

__device__ __forceinline__ short8 pack8(float4 a, float4 b) {
    short8 v;
    v[0] = f2bf(a.x); v[1] = f2bf(a.y); v[2] = f2bf(a.z); v[3] = f2bf(a.w);
    v[4] = f2bf(b.x); v[5] = f2bf(b.y); v[6] = f2bf(b.z); v[7] = f2bf(b.w);
    return v;
}

// ---------------- K1: amplitude pipeline (1 block, 1024 threads) ----------------
__global__ __launch_bounds__(1024) void k_amps(const float* __restrict__ AR,
                                               const float* __restrict__ AI,
                                               const float* __restrict__ H,
                                               float* __restrict__ out,
                                               float* __restrict__ w) {
    __shared__ float redA[16 * NSTATES];
    __shared__ float redB[16 * 10];
    __shared__ float norms[NSTATES];
    __shared__ float sA[8][8], sA2[8][8], sA3[8][8];
    __shared__ float Ur[8][8], Ui[8][8];
    __shared__ float lamsa[2];

    const int tid = threadIdx.x;
    const int lane = tid & 63, wid = tid >> 6;
    const int d = tid;

    float arv[NSTATES], aiv[NSTATES];
    #pragma unroll
    for (int s = 0; s < NSTATES; s++) {
        arv[s] = AR[s * HD + d];
        aiv[s] = AI[s * HD + d];
    }
    float p[NSTATES];
    #pragma unroll
    for (int s = 0; s < NSTATES; s++) p[s] = arv[s] * arv[s] + aiv[s] * aiv[s];
    #pragma unroll
    for (int s = 0; s < NSTATES; s++)
        #pragma unroll
        for (int o = 32; o > 0; o >>= 1) p[s] += __shfl_down(p[s], o, 64);
    if (lane == 0)
        #pragma unroll
        for (int s = 0; s < NSTATES; s++) redA[wid * NSTATES + s] = p[s];
    if (tid < 64) {
        int i = tid >> 3, j = tid & 7;
        sA[i][j] = 0.5f * (H[i * 8 + j] + H[j * 8 + i]) * 0.01f;  // DT/PLANCK
    }
    __syncthreads();
    if (tid < 8) {
        float acc = 0.f;
        #pragma unroll
        for (int v = 0; v < 16; v++) acc += redA[v * NSTATES + tid];
        norms[tid] = acc;
    }
    if (tid < 64) {
        int i = tid >> 3, j = tid & 7;
        float acc = 0.f;
        #pragma unroll
        for (int k = 0; k < 8; k++) acc += sA[i][k] * sA[k][j];
        sA2[i][j] = acc;
    }
    __syncthreads();
    if (tid < 64) {
        int i = tid >> 3, j = tid & 7;
        float acc = 0.f;
        #pragma unroll
        for (int k = 0; k < 8; k++) acc += sA2[i][k] * sA[k][j];
        sA3[i][j] = acc;
        Ur[i][j] = ((i == j) ? 1.f : 0.f) - 0.5f * sA2[i][j];   // cos(A)
        Ui[i][j] = -(sA[i][j] - sA3[i][j] * (1.f / 6.f));       // -sin(A)
    }
    __syncthreads();

    #pragma unroll
    for (int s = 0; s < NSTATES; s++) {
        float inv = 1.0f / sqrtf(norms[s] + 1e-8f);
        arv[s] *= inv;
        aiv[s] *= inv;
    }
    float nr[NSTATES], ni[NSTATES];
    #pragma unroll
    for (int s = 0; s < NSTATES; s++) {
        float xr = 0.f, xi = 0.f;
        #pragma unroll
        for (int t = 0; t < NSTATES; t++) {
            float ur = Ur[s][t], ui = Ui[s][t];
            xr += ur * arv[t] - ui * aiv[t];
            xi += ur * aiv[t] + ui * arv[t];
        }
        nr[s] = xr; ni[s] = xi;
    }
    float dist[NSTATES], csum = 0.f, sabs = 0.f;
    #pragma unroll
    for (int s = 0; s < NSTATES; s++) {
        dist[s] = nr[s] * nr[s] + ni[s] * ni[s];
        csum += dist[s];
        sabs += sqrtf(dist[s]);
    }
    #pragma unroll
    for (int s = 0; s < NSTATES; s++) {
        out[OUT_AD + s * HD + d] = dist[s];
        out[OUT_PH + s * HD + d] = atan2f(ni[s], nr[s]);
        w[s * HD + d] = nr[s];
    }
    float cinv = 1.0f / (csum + 1e-8f);
    float q[10];
    #pragma unroll
    for (int s = 0; s < NSTATES; s++) q[s] = dist[s] * cinv;
    q[8] = csum; q[9] = sabs;
    #pragma unroll
    for (int v = 0; v < 10; v++)
        #pragma unroll
        for (int o = 32; o > 0; o >>= 1) q[v] += __shfl_down(q[v], o, 64);
    if (lane == 0)
        #pragma unroll
        for (int v = 0; v < 10; v++) redB[wid * 10 + v] = q[v];
    __syncthreads();
    if (tid < 10) {
        float acc = 0.f;
        #pragma unroll
        for (int v = 0; v < 16; v++) acc += redB[v * 10 + tid];
        if (tid < 8)       out[OUT_CP + tid] = acc * (1.0f / HD);
        else               lamsa[tid - 8] = acc;
    }
    __syncthreads();
    if (tid == 0) {
        float lam = lamsa[0], sa = lamsa[1];
        out[OUT_ENT] = -(lam * logf(lam + 1e-12f));
        out[OUT_COH] = sa * sa - lam;
    }
}

// ------- K3: fused project + transpose: Mt[e,d] = bf16( sum_s w[s,e]*P[s,d,e] ) -
__global__ __launch_bounds__(256) void k_project_t(const float* __restrict__ P,
                                                   const float* __restrict__ w,
                                                   short* __restrict__ Mt) {
    __shared__ float tile[64][65];
    int d0 = (blockIdx.x >> 4) * 64;
    int e0 = (blockIdx.x & 15) * 64;
    int tx = threadIdx.x & 63, ty = threadIdx.x >> 6;
    float wv[NSTATES];
    #pragma unroll
    for (int s = 0; s < NSTATES; s++) wv[s] = w[s * HD + e0 + tx];
    #pragma unroll
    for (int j = 0; j < 16; j++) {
        int r = ty + 4 * j;
        float acc = 0.f;
        #pragma unroll
        for (int s = 0; s < NSTATES; s++)
            acc += wv[s] * P[(size_t)s * HD * HD + (size_t)(d0 + r) * HD + e0 + tx];
        tile[r][tx] = acc;
    }
    __syncthreads();
    #pragma unroll
    for (int j = 0; j < 16; j++) {
        int er = ty + 4 * j;
        Mt[(size_t)(e0 + er) * HD + d0 + tx] = f2bf(tile[tx][er]);
    }
}

// ---------------- K4: out = bf16(X) @ Mt^T  -- 256^2 quadrant-phase, fused cast -
// 512 threads = 8 waves (2M x 4N per quadrant). A reg-staged from fp32 X (T14
// issue-early/write-late, in-kernel bf16 cast); B via global_load_lds. T1 XCD
// swizzle + T2 both-sides LDS XOR-swizzle + counted vmcnt + T5 setprio.

__device__ __forceinline__ void stage_half_B(const short* __restrict__ srcBase,
                                             int rowbase, int h, int t2,
                                             short* dst, const int* goff,
                                             const int* ldsoff) {
    #pragma unroll
    for (int i = 0; i < 2; i++) {
        const short* g = srcBase + (size_t)(rowbase + h * 128) * HD + t2 * 64 + goff[i];
        __builtin_amdgcn_global_load_lds(
            (const __attribute__((address_space(1))) void*)g,
            (__attribute__((address_space(3))) void*)(dst + h * 8192 + ldsoff[i]),
            16, 0, 0);
    }
}

#define XLOAD(h, t2)                                                           \
    {                                                                          \
        const float* base_ = X + (size_t)(brow + (h) * 128) * HD + (t2) * 64;  \
        xr[0] = *reinterpret_cast<const float4*>(base_ + goff[0]);             \
        xr[1] = *reinterpret_cast<const float4*>(base_ + goff[0] + 4);         \
        xr[2] = *reinterpret_cast<const float4*>(base_ + goff[1]);             \
        xr[3] = *reinterpret_cast<const float4*>(base_ + goff[1] + 4);         \
    }

#define XWRITE(dst, h)                                                         \
    {                                                                          \
        *reinterpret_cast<short8*>((dst) + (h) * 8192 + ldsoff[0]) = pack8(xr[0], xr[1]); \
        *reinterpret_cast<short8*>((dst) + (h) * 8192 + ldsoff[1]) = pack8(xr[2], xr[3]); \
    }

#define LOAD_A(qa)                                                             \
    _Pragma("unroll") for (int mf = 0; mf < 4; mf++)                           \
    _Pragma("unroll") for (int kk = 0; kk < 2; kk++)                           \
        af[mf][kk] = *reinterpret_cast<const short8*>(                         \
            &Acur[((qa) * 128 + wr64 + mf * 16 + ln15) * 64 + kx[kk]]);

#define LOAD_B(qb)                                                             \
    _Pragma("unroll") for (int nf = 0; nf < 2; nf++)                           \
    _Pragma("unroll") for (int kk = 0; kk < 2; kk++)                           \
        bf[nf][kk] = *reinterpret_cast<const short8*>(                         \
            &Bcur[((qb) * 128 + wn32 + nf * 16 + ln15) * 64 + kx[kk]]);

#define MFMA_P(qa, qb)                                                         \
    _Pragma("unroll") for (int mf = 0; mf < 4; mf++)                           \
    _Pragma("unroll") for (int nf = 0; nf < 2; nf++)                           \
    _Pragma("unroll") for (int kk = 0; kk < 2; kk++)                           \
        acc[(qa) * 4 + mf][(qb) * 2 + nf] =                                    \
            __builtin_amdgcn_mfma_f32_16x16x32_bf16(                           \
                af[mf][kk], bf[nf][kk], acc[(qa) * 4 + mf][(qb) * 2 + nf], 0, 0, 0);

#define PHASE_MID()                                                            \
    __builtin_amdgcn_s_barrier();                                              \
    __builtin_amdgcn_s_setprio(1);

#define PHASE_END()                                                            \
    __builtin_amdgcn_s_setprio(0);                                             \
    __builtin_amdgcn_s_barrier();

__global__ __launch_bounds__(512, 1) void k_gemm_8p(const float* __restrict__ X,
                                                    const short* __restrict__ Mt,
                                                    float* __restrict__ out) {
    __shared__ short As[2][256 * 64];   // 64 KiB: [buf][half*128+row][kchunk]
    __shared__ short Bs[2][256 * 64];   // 64 KiB

    const int bid = blockIdx.x;                       // 256 blocks (64 bm x 4 bn)
    const int swz = (bid & 7) * 32 + (bid >> 3);      // XCD-contiguous, bijective
    const int brow = (swz >> 2) * 256;
    const int bcol = (swz & 3) * 256;

    const int tid  = threadIdx.x;
    const int lane = tid & 63, wid = tid >> 6;
    const int wr = wid >> 2, wn = wid & 3;
    const int ln15 = lane & 15, l16 = lane >> 4;
    const int wr64 = wr * 64;
    const int wn32 = wn * 32;

    // ds_read swizzled k-chunk offsets (shorts): chunk = kg ^ (row&7); row&7==ln15&7
    int kx[2];
    kx[0] = ((l16 + 0) ^ (ln15 & 7)) * 8;
    kx[1] = ((l16 + 4) ^ (ln15 & 7)) * 8;

    // staging offsets (element counts): LDS linear dest, inverse-swizzled source
    int goff[2], ldsoff[2];
    #pragma unroll
    for (int i = 0; i < 2; i++) {
        int c = tid + 512 * i;
        int row = c >> 3, kc = c & 7;
        goff[i]   = row * HD + ((kc ^ (row & 7)) * 8);
        ldsoff[i] = c * 8;
    }

    short* A0 = &As[0][0]; short* A1b = &As[1][0];
    short* B0 = &Bs[0][0]; short* B1b = &Bs[1][0];

    f32x4 acc[8][4];
    #pragma unroll
    for (int m = 0; m < 8; m++)
        #pragma unroll
        for (int n = 0; n < 4; n++) acc[m][n] = (f32x4){0.f, 0.f, 0.f, 0.f};

    float4 xr[4];

    // prologue: X(0) both halves -> A0; B(0) both halves; B-hi(1).
    XLOAD(0, 0);
    float4 xr2[4];
    {
        const float* base_ = X + (size_t)(brow + 128) * HD;
        xr2[0] = *reinterpret_cast<const float4*>(base_ + goff[0]);
        xr2[1] = *reinterpret_cast<const float4*>(base_ + goff[0] + 4);
        xr2[2] = *reinterpret_cast<const float4*>(base_ + goff[1]);
        xr2[3] = *reinterpret_cast<const float4*>(base_ + goff[1] + 4);
    }
    stage_half_B(Mt, bcol, 0, 0, B0, goff, ldsoff);
    stage_half_B(Mt, bcol, 1, 0, B0, goff, ldsoff);
    stage_half_B(Mt, bcol, 1, 1, B1b, goff, ldsoff);
    XWRITE(A0, 0);
    *reinterpret_cast<short8*>(A0 + 8192 + ldsoff[0]) = pack8(xr2[0], xr2[1]);
    *reinterpret_cast<short8*>(A0 + 8192 + ldsoff[1]) = pack8(xr2[2], xr2[3]);
    asm volatile("s_waitcnt vmcnt(2) lgkmcnt(0)" ::: "memory");  // B(0) + A-writes done
    __builtin_amdgcn_s_barrier();

    short8 af[4][2], bf[2][2];

    #pragma unroll 1
    for (int t = 0; t < NT; t++) {
        const int cur = t & 1;
        short* Acur  = cur ? A1b : A0;
        short* Bcur  = cur ? B1b : B0;
        short* Anext = cur ? A0 : A1b;   // buf of t+1
        short* Bnext = cur ? B0 : B1b;

        // ---- ph1: quadrant (0,0); issue X-lo(t+1)
        LOAD_A(0); LOAD_B(0);
        if (t + 1 < NT) XLOAD(0, (t + 1));
        PHASE_MID();
        MFMA_P(0, 0);
        PHASE_END();

        // ---- ph2: quadrant (0,1); write A-lo(t+1); DMA B-lo(t+1)
        LOAD_B(1);
        if (t + 1 < NT) {
            stage_half_B(Mt, bcol, 0, t + 1, Bnext, goff, ldsoff);
            XWRITE(Anext, 0);
        }
        PHASE_MID();
        MFMA_P(0, 1);
        __builtin_amdgcn_s_setprio(0);
        asm volatile("s_waitcnt lgkmcnt(0)" ::: "memory");   // publish A-lo writes
        __builtin_amdgcn_s_barrier();

        // ---- ph3: quadrant (1,1); issue X-hi(t+1)
        LOAD_A(1);
        if (t + 1 < NT) XLOAD(1, (t + 1));
        PHASE_MID();
        MFMA_P(1, 1);
        PHASE_END();

        // ---- ph4: quadrant (1,0); write A-hi(t+1); DMA B-hi(t+2) into cur
        LOAD_B(0);
        if (t + 1 < NT) XWRITE(Anext, 1);
        if (t + 2 < NT) stage_half_B(Mt, bcol, 1, t + 2, Bcur, goff, ldsoff);
        PHASE_MID();
        MFMA_P(1, 0);
        __builtin_amdgcn_s_setprio(0);
        // drain: A-hi writes (lgkm) + all B(t+1) loads; keep B-hi(t+2) in flight
        if (t + 2 < NT) asm volatile("s_waitcnt vmcnt(2) lgkmcnt(0)" ::: "memory");
        else            asm volatile("s_waitcnt vmcnt(0) lgkmcnt(0)" ::: "memory");
        __builtin_amdgcn_s_barrier();
    }

    // epilogue: C/D layout col=lane&15, row=(lane>>4)*4+j  [m89-verified]
    #pragma unroll
    for (int qa = 0; qa < 2; qa++)
        #pragma unroll
        for (int mf = 0; mf < 4; mf++)
            #pragma unroll
            for (int qb = 0; qb < 2; qb++)
                #pragma unroll
                for (int nf = 0; nf < 2; nf++)
                    #pragma unroll
                    for (int j = 0; j < 4; j++) {
                        int r = brow + qa * 128 + wr64 + mf * 16 + l16 * 4 + j;
                        int c = bcol + qb * 128 + wn32 + nf * 16 + ln15;
                        out[(size_t)r * HD + c] = acc[qa * 4 + mf][qb * 2 + nf][j];
                    }
}

extern "C" void kernel_launch(void* const* d_in, const int* in_sizes, int n_in,
                              void* d_out, int out_size, void* d_ws, size_t ws_size,
                              hipStream_t stream) {
    const float* X  = (const float*)d_in[0];  // [16384,1024]
    const float* AR = (const float*)d_in[1];
    const float* AI = (const float*)d_in[2];
    const float* H  = (const float*)d_in[3];
    const float* P  = (const float*)d_in[4];  // [8,1024,1024]
    float* out = (float*)d_out;

    char* ws = (char*)d_ws;
    float* w  = (float*)ws;                       // 32 KB
    short* Mt = (short*)(ws + 32768);             // 2 MB  (bf16 M^T)

    k_amps<<<1, 1024, 0, stream>>>(AR, AI, H, out, w);
    k_project_t<<<256, 256, 0, stream>>>(P, w, Mt);
    k_gemm_8p<<<(NBATCH / 256) * (HD / 256), 512, 0, stream>>>(X, Mt, out);
}

// Round 6
// 73.985 us; speedup vs baseline: 1.4609x; 1.0330x over previous
//
#include <hip/hip_runtime.h>
#include <hip/hip_bf16.h>

#define NSTATES 8
#define HD      1024
#define NBATCH  16384
#define NT      16      // K-tiles of 64

// output layout (flat fp32, return order)
#define OUT_MEAS 0
#define OUT_CP   16777216
#define OUT_ENT  16777224
#define OUT_COH  16777225
#define OUT_AD   16777226
#define OUT_PH   16785418

typedef __attribute__((ext_vector_type(8))) short short8;
typedef __attribute__((ext_vector_type(4))) float f32x4;

__device__ __forceinline__ short f2bf(float f) {
    union { float f; unsigned u; } x; x.f = f;
    unsigned r = x.u + 0x7fffu + ((x.u >> 16) & 1u);  // RNE
    return (short)(r >> 16);
}

__device__ __forceinline__ short8 pack8(float4 a, float4 b) {
    short8 v;
    v[0] = f2bf(a.x); v[1] = f2bf(a.y); v[2] = f2bf(a.z); v[3] = f2bf(a.w);
    v[4] = f2bf(b.x); v[5] = f2bf(b.y); v[6] = f2bf(b.z); v[7] = f2bf(b.w);
    return v;
}

// ---------------- K1: amplitude pipeline (1 block, 1024 threads) ----------------
__global__ __launch_bounds__(1024) void k_amps(const float* __restrict__ AR,
                                               const float* __restrict__ AI,
                                               const float* __restrict__ H,
                                               float* __restrict__ out,
                                               float* __restrict__ w) {
    __shared__ float redA[16 * NSTATES];
    __shared__ float redB[16 * 10];
    __shared__ float norms[NSTATES];
    __shared__ float sA[8][8], sA2[8][8], sA3[8][8];
    __shared__ float Ur[8][8], Ui[8][8];
    __shared__ float lamsa[2];

    const int tid = threadIdx.x;
    const int lane = tid & 63, wid = tid >> 6;
    const int d = tid;

    float arv[NSTATES], aiv[NSTATES];
    #pragma unroll
    for (int s = 0; s < NSTATES; s++) {
        arv[s] = AR[s * HD + d];
        aiv[s] = AI[s * HD + d];
    }
    float p[NSTATES];
    #pragma unroll
    for (int s = 0; s < NSTATES; s++) p[s] = arv[s] * arv[s] + aiv[s] * aiv[s];
    #pragma unroll
    for (int s = 0; s < NSTATES; s++)
        #pragma unroll
        for (int o = 32; o > 0; o >>= 1) p[s] += __shfl_down(p[s], o, 64);
    if (lane == 0)
        #pragma unroll
        for (int s = 0; s < NSTATES; s++) redA[wid * NSTATES + s] = p[s];
    if (tid < 64) {
        int i = tid >> 3, j = tid & 7;
        sA[i][j] = 0.5f * (H[i * 8 + j] + H[j * 8 + i]) * 0.01f;  // DT/PLANCK
    }
    __syncthreads();
    if (tid < 8) {
        float acc = 0.f;
        #pragma unroll
        for (int v = 0; v < 16; v++) acc += redA[v * NSTATES + tid];
        norms[tid] = acc;
    }
    if (tid < 64) {
        int i = tid >> 3, j = tid & 7;
        float acc = 0.f;
        #pragma unroll
        for (int k = 0; k < 8; k++) acc += sA[i][k] * sA[k][j];
        sA2[i][j] = acc;
    }
    __syncthreads();
    if (tid < 64) {
        int i = tid >> 3, j = tid & 7;
        float acc = 0.f;
        #pragma unroll
        for (int k = 0; k < 8; k++) acc += sA2[i][k] * sA[k][j];
        sA3[i][j] = acc;
        Ur[i][j] = ((i == j) ? 1.f : 0.f) - 0.5f * sA2[i][j];   // cos(A)
        Ui[i][j] = -(sA[i][j] - sA3[i][j] * (1.f / 6.f));       // -sin(A)
    }
    __syncthreads();

    #pragma unroll
    for (int s = 0; s < NSTATES; s++) {
        float inv = 1.0f / sqrtf(norms[s] + 1e-8f);
        arv[s] *= inv;
        aiv[s] *= inv;
    }
    float nr[NSTATES], ni[NSTATES];
    #pragma unroll
    for (int s = 0; s < NSTATES; s++) {
        float xr = 0.f, xi = 0.f;
        #pragma unroll
        for (int t = 0; t < NSTATES; t++) {
            float ur = Ur[s][t], ui = Ui[s][t];
            xr += ur * arv[t] - ui * aiv[t];
            xi += ur * aiv[t] + ui * arv[t];
        }
        nr[s] = xr; ni[s] = xi;
    }
    float dist[NSTATES], csum = 0.f, sabs = 0.f;
    #pragma unroll
    for (int s = 0; s < NSTATES; s++) {
        dist[s] = nr[s] * nr[s] + ni[s] * ni[s];
        csum += dist[s];
        sabs += sqrtf(dist[s]);
    }
    #pragma unroll
    for (int s = 0; s < NSTATES; s++) {
        out[OUT_AD + s * HD + d] = dist[s];
        out[OUT_PH + s * HD + d] = atan2f(ni[s], nr[s]);
        w[s * HD + d] = nr[s];
    }
    float cinv = 1.0f / (csum + 1e-8f);
    float q[10];
    #pragma unroll
    for (int s = 0; s < NSTATES; s++) q[s] = dist[s] * cinv;
    q[8] = csum; q[9] = sabs;
    #pragma unroll
    for (int v = 0; v < 10; v++)
        #pragma unroll
        for (int o = 32; o > 0; o >>= 1) q[v] += __shfl_down(q[v], o, 64);
    if (lane == 0)
        #pragma unroll
        for (int v = 0; v < 10; v++) redB[wid * 10 + v] = q[v];
    __syncthreads();
    if (tid < 10) {
        float acc = 0.f;
        #pragma unroll
        for (int v = 0; v < 16; v++) acc += redB[v * 10 + tid];
        if (tid < 8)       out[OUT_CP + tid] = acc * (1.0f / HD);
        else               lamsa[tid - 8] = acc;
    }
    __syncthreads();
    if (tid == 0) {
        float lam = lamsa[0], sa = lamsa[1];
        out[OUT_ENT] = -(lam * logf(lam + 1e-12f));
        out[OUT_COH] = sa * sa - lam;
    }
}

// ------- K3: fused project + transpose: Mt[e,d] = bf16( sum_s w[s,e]*P[s,d,e] ) -
__global__ __launch_bounds__(256) void k_project_t(const float* __restrict__ P,
                                                   const float* __restrict__ w,
                                                   short* __restrict__ Mt) {
    __shared__ float tile[64][65];
    int d0 = (blockIdx.x >> 4) * 64;
    int e0 = (blockIdx.x & 15) * 64;
    int tx = threadIdx.x & 63, ty = threadIdx.x >> 6;
    float wv[NSTATES];
    #pragma unroll
    for (int s = 0; s < NSTATES; s++) wv[s] = w[s * HD + e0 + tx];
    #pragma unroll
    for (int j = 0; j < 16; j++) {
        int r = ty + 4 * j;
        float acc = 0.f;
        #pragma unroll
        for (int s = 0; s < NSTATES; s++)
            acc += wv[s] * P[(size_t)s * HD * HD + (size_t)(d0 + r) * HD + e0 + tx];
        tile[r][tx] = acc;
    }
    __syncthreads();
    #pragma unroll
    for (int j = 0; j < 16; j++) {
        int er = ty + 4 * j;
        Mt[(size_t)(e0 + er) * HD + d0 + tx] = f2bf(tile[tx][er]);
    }
}

// ---------------- K4: out = bf16(X) @ Mt^T  -- JIT single-A quadrant-phase -----
// 512 threads = 8 waves (2M x 4N per quadrant). Quadrant order (0,0),(0,1),(1,1),
// (1,0): LDS A-lo dead after ph1 reads, A-hi dead after ph3 -> SINGLE A buffer,
// just-in-time written. One 16-reg X window, issue->consume distance 2 phases:
//   ph2(t): ds_write lo(t+1), issue hi(t+1);  ph4(t): ds_write hi(t+1), issue lo(t+2)
// B double-buffered via global_load_lds, counted vmcnt(6) at tile end.

__device__ __forceinline__ void stage_half_B(const short* __restrict__ srcBase,
                                             int rowbase, int h, int t2,
                                             short* dst, const int* goff,
                                             const int* ldsoff) {
    #pragma unroll
    for (int i = 0; i < 2; i++) {
        const short* g = srcBase + (size_t)(rowbase + h * 128) * HD + t2 * 64 + goff[i];
        __builtin_amdgcn_global_load_lds(
            (const __attribute__((address_space(1))) void*)g,
            (__attribute__((address_space(3))) void*)(dst + h * 8192 + ldsoff[i]),
            16, 0, 0);
    }
}

#define XLOAD_TO(dst, h, t2)                                                   \
    {                                                                          \
        const float* base_ = X + (size_t)(brow + (h) * 128) * HD + (t2) * 64;  \
        dst[0] = *reinterpret_cast<const float4*>(base_ + goff[0]);            \
        dst[1] = *reinterpret_cast<const float4*>(base_ + goff[0] + 4);        \
        dst[2] = *reinterpret_cast<const float4*>(base_ + goff[1]);            \
        dst[3] = *reinterpret_cast<const float4*>(base_ + goff[1] + 4);        \
    }

#define XWRITE_FROM(src, h)                                                    \
    {                                                                          \
        *reinterpret_cast<short8*>(As + (h) * 8192 + ldsoff[0]) = pack8(src[0], src[1]); \
        *reinterpret_cast<short8*>(As + (h) * 8192 + ldsoff[1]) = pack8(src[2], src[3]); \
    }

#define LOAD_A(qa)                                                             \
    _Pragma("unroll") for (int mf = 0; mf < 4; mf++)                           \
    _Pragma("unroll") for (int kk = 0; kk < 2; kk++)                           \
        af[mf][kk] = *reinterpret_cast<const short8*>(                         \
            &As[((qa) * 128 + wr64 + mf * 16 + ln15) * 64 + kx[kk]]);

#define LOAD_B(qb)                                                             \
    _Pragma("unroll") for (int nf = 0; nf < 2; nf++)                           \
    _Pragma("unroll") for (int kk = 0; kk < 2; kk++)                           \
        bf[nf][kk] = *reinterpret_cast<const short8*>(                         \
            &Bcur[((qb) * 128 + wn32 + nf * 16 + ln15) * 64 + kx[kk]]);

#define MFMA_P(qa, qb)                                                         \
    _Pragma("unroll") for (int mf = 0; mf < 4; mf++)                           \
    _Pragma("unroll") for (int nf = 0; nf < 2; nf++)                           \
    _Pragma("unroll") for (int kk = 0; kk < 2; kk++)                           \
        acc[(qa) * 4 + mf][(qb) * 2 + nf] =                                    \
            __builtin_amdgcn_mfma_f32_16x16x32_bf16(                           \
                af[mf][kk], bf[nf][kk], acc[(qa) * 4 + mf][(qb) * 2 + nf], 0, 0, 0);

#define PHASE_MID()                                                            \
    __builtin_amdgcn_s_barrier();                                              \
    __builtin_amdgcn_s_setprio(1);

#define PHASE_END()                                                            \
    __builtin_amdgcn_s_setprio(0);                                             \
    __builtin_amdgcn_s_barrier();

__global__ __launch_bounds__(512, 1) void k_gemm_8p(const float* __restrict__ X,
                                                    const short* __restrict__ Mt,
                                                    float* __restrict__ out) {
    __shared__ short As[256 * 64];      // 32 KiB single buffer, JIT-written
    __shared__ short Bs[2][256 * 64];   // 64 KiB double-buffered

    const int bid = blockIdx.x;                       // 256 blocks (64 bm x 4 bn)
    const int swz = (bid & 7) * 32 + (bid >> 3);      // XCD-contiguous, bijective
    const int brow = (swz >> 2) * 256;
    const int bcol = (swz & 3) * 256;

    const int tid  = threadIdx.x;
    const int lane = tid & 63, wid = tid >> 6;
    const int wr = wid >> 2, wn = wid & 3;
    const int ln15 = lane & 15, l16 = lane >> 4;
    const int wr64 = wr * 64;
    const int wn32 = wn * 32;

    // ds_read swizzled k-chunk offsets (shorts): chunk = kg ^ (row&7); row&7==ln15&7
    int kx[2];
    kx[0] = ((l16 + 0) ^ (ln15 & 7)) * 8;
    kx[1] = ((l16 + 4) ^ (ln15 & 7)) * 8;

    // staging offsets (element counts): LDS linear dest, inverse-swizzled source
    int goff[2], ldsoff[2];
    #pragma unroll
    for (int i = 0; i < 2; i++) {
        int c = tid + 512 * i;
        int row = c >> 3, kc = c & 7;
        goff[i]   = row * HD + ((kc ^ (row & 7)) * 8);
        ldsoff[i] = c * 8;
    }

    short* B0 = &Bs[0][0]; short* B1 = &Bs[1][0];

    f32x4 acc[8][4];
    #pragma unroll
    for (int m = 0; m < 8; m++)
        #pragma unroll
        for (int n = 0; n < 4; n++) acc[m][n] = (f32x4){0.f, 0.f, 0.f, 0.f};

    float4 xr[4];          // shared X staging window (alternates lo/hi)

    // ---- prologue ----
    {
        float4 t0[4], t1[4];
        XLOAD_TO(t0, 0, 0);
        XLOAD_TO(t1, 1, 0);
        stage_half_B(Mt, bcol, 0, 0, B0, goff, ldsoff);
        stage_half_B(Mt, bcol, 1, 0, B0, goff, ldsoff);
        XWRITE_FROM(t0, 0);               // compiler waits t0/t1 loads
        XWRITE_FROM(t1, 1);
        stage_half_B(Mt, bcol, 1, 1, B1, goff, ldsoff);   // B-hi(1)
        XLOAD_TO(xr, 0, 1);               // lo(1) -> xr
    }
    // need B(0) landed + As writes published; keep Bhi(1)+xr in flight
    asm volatile("s_waitcnt vmcnt(6) lgkmcnt(0)" ::: "memory");
    __builtin_amdgcn_s_barrier();

    short8 af[4][2], bf[2][2];

    #pragma unroll 1
    for (int t = 0; t < NT; t++) {
        short* Bcur  = (t & 1) ? B1 : B0;
        short* Bnext = (t & 1) ? B0 : B1;

        // ---- ph1: quadrant (0,0)  [pure compute]
        LOAD_A(0); LOAD_B(0);
        PHASE_MID();
        MFMA_P(0, 0);
        PHASE_END();

        // ---- ph2: quadrant (0,1); write lo(t+1), issue hi(t+1), DMA B-lo(t+1)
        LOAD_B(1);
        if (t + 1 < NT) {
            XWRITE_FROM(xr, 0);                            // lo(t+1) -> As-lo
            XLOAD_TO(xr, 1, (t + 1));                      // issue hi(t+1)
            stage_half_B(Mt, bcol, 0, t + 1, Bnext, goff, ldsoff);
        }
        PHASE_MID();
        MFMA_P(0, 1);
        __builtin_amdgcn_s_setprio(0);
        asm volatile("s_waitcnt lgkmcnt(0)" ::: "memory"); // publish As-lo writes
        __builtin_amdgcn_s_barrier();

        // ---- ph3: quadrant (1,1)  [pure compute]
        LOAD_A(1);
        PHASE_MID();
        MFMA_P(1, 1);
        PHASE_END();

        // ---- ph4: quadrant (1,0); write hi(t+1), issue lo(t+2), DMA B-hi(t+2)
        LOAD_B(0);
        if (t + 1 < NT) XWRITE_FROM(xr, 1);                // hi(t+1) -> As-hi
        if (t + 2 < NT) {
            XLOAD_TO(xr, 0, (t + 2));                      // issue lo(t+2)
            stage_half_B(Mt, bcol, 1, t + 2, Bcur, goff, ldsoff);
        }
        PHASE_MID();
        MFMA_P(1, 0);
        __builtin_amdgcn_s_setprio(0);
        // outstanding: [Bhi(t+1):2, Blo(t+1):2, lo(t+2):4, Bhi(t+2):2]
        if (t + 2 < NT)      asm volatile("s_waitcnt vmcnt(6) lgkmcnt(0)" ::: "memory");
        else if (t + 1 < NT) asm volatile("s_waitcnt vmcnt(0) lgkmcnt(0)" ::: "memory");
        __builtin_amdgcn_s_barrier();
    }

    // epilogue: C/D layout col=lane&15, row=(lane>>4)*4+j  [m89-verified]
    #pragma unroll
    for (int qa = 0; qa < 2; qa++)
        #pragma unroll
        for (int mf = 0; mf < 4; mf++)
            #pragma unroll
            for (int qb = 0; qb < 2; qb++)
                #pragma unroll
                for (int nf = 0; nf < 2; nf++)
                    #pragma unroll
                    for (int j = 0; j < 4; j++) {
                        int r = brow + qa * 128 + wr64 + mf * 16 + l16 * 4 + j;
                        int c = bcol + qb * 128 + wn32 + nf * 16 + ln15;
                        out[(size_t)r * HD + c] = acc[qa * 4 + mf][qb * 2 + nf][j];
                    }
}

extern "C" void kernel_launch(void* const* d_in, const int* in_sizes, int n_in,
                              void* d_out, int out_size, void* d_ws, size_t ws_size,
                              hipStream_t stream) {
    const float* X  = (const float*)d_in[0];  // [16384,1024]
    const float* AR = (const float*)d_in[1];
    const float* AI = (const float*)d_in[2];
    const float* H  = (const float*)d_in[3];
    const float* P  = (const float*)d_in[4];  // [8,1024,1024]
    float* out = (float*)d_out;

    char* ws = (char*)d_ws;
    float* w  = (float*)ws;                       // 32 KB
    short* Mt = (short*)(ws + 32768);             // 2 MB  (bf16 M^T)

    k_amps<<<1, 1024, 0, stream>>>(AR, AI, H, out, w);
    k_project_t<<<256, 256, 0, stream>>>(P, w, Mt);
    k_gemm_8p<<<(NBATCH / 256) * (HD / 256), 512, 0, stream>>>(X, Mt, out);
}